// Round 9
// baseline (313.109 us; speedup 1.0000x reference)
//
#include <hip/hip_runtime.h>
#include <hip/hip_bf16.h>
#include <math.h>

// Problem constants
#define TT 1024
#define DIM 1024
#define HH 8
#define QLR 768
#define KVLR 512
#define DNOPE 128
#define DROPE 64
#define DV 128
#define DK 192            // DNOPE + DROPE
#define HDK (HH*DK)       // 1536
#define HKV (HH*(DNOPE+DV)) // 2048

// Phase-A blob layout (floats) per (chunk n, head h):
#define OY   0
#define OQ   3072
#define OC   6144         // KcT [192][20] padded; slot 16 of each row = lam[d]
#define OPL  9984
#define OU   10240        // u' transposed: [128 cc][16 ti]
#define OLAM 12288
#define PABLK 12480

typedef __attribute__((ext_vector_type(8))) short short8;
typedef __attribute__((ext_vector_type(4))) float f32x4;

// ---------------------------------------------------------------------------
// bf16 split helpers
// ---------------------------------------------------------------------------
__device__ __forceinline__ unsigned short f2bf_rn(float f) {
    unsigned u = __float_as_uint(f);
    unsigned lsb = (u >> 16) & 1u;
    u += 0x7fffu + lsb;
    return (unsigned short)(u >> 16);
}
__device__ __forceinline__ float bf2f(unsigned short h) {
    return __uint_as_float(((unsigned)h) << 16);
}

// ---------------------------------------------------------------------------
// Weight transpose+split: W[K][N] f32 -> Wt_h[N][K], Wt_l[N][K] bf16.
// ---------------------------------------------------------------------------
__global__ __launch_bounds__(256) void wconv(
    const float* __restrict__ W0, unsigned short* __restrict__ H0,
    unsigned short* __restrict__ L0, int K0, int N0, int T0,
    const float* __restrict__ W1, unsigned short* __restrict__ H1,
    unsigned short* __restrict__ L1, int K1, int N1, int T1,
    const float* __restrict__ W2, unsigned short* __restrict__ H2,
    unsigned short* __restrict__ L2, int K2, int N2, int T2)
{
    __shared__ float Ls[64][65];
    int bx = blockIdx.x;
    const float* W; unsigned short* H; unsigned short* L; int K, N;
    if (bx < T0)           { W = W0; H = H0; L = L0; K = K0; N = N0; }
    else if (bx < T0 + T1) { bx -= T0; W = W1; H = H1; L = L1; K = K1; N = N1; }
    else                   { bx -= T0 + T1; W = W2; H = H2; L = L2; K = K2; N = N2; }

    const int NT = N >> 6;
    const int kt = bx / NT, nt = bx - kt * NT;
    const int k0 = kt * 64, n0 = nt * 64;
    const int tid = threadIdx.x;
    const int r = tid >> 2, c = (tid & 3) * 16;

#pragma unroll
    for (int i = 0; i < 4; i++)
        *(float4*)&Ls[r][c + i * 4] =
            *(const float4*)&W[(size_t)(k0 + r) * N + n0 + c + i * 4];
    __syncthreads();

    const int nr = tid >> 2, kc = (tid & 3) * 16;
    unsigned short hb[16], lb[16];
#pragma unroll
    for (int j = 0; j < 16; j++) {
        float v = Ls[kc + j][nr];
        unsigned short h = f2bf_rn(v);
        hb[j] = h;
        lb[j] = f2bf_rn(v - bf2f(h));
    }
    size_t ob = (size_t)(n0 + nr) * K + k0 + kc;
    *(float4*)&H[ob]     = ((float4*)hb)[0];
    *(float4*)&H[ob + 8] = ((float4*)hb)[1];
    *(float4*)&L[ob]     = ((float4*)lb)[0];
    *(float4*)&L[ob + 8] = ((float4*)lb)[1];
}

// ---------------------------------------------------------------------------
// Activation split: A f32 -> H, L bf16.
// ---------------------------------------------------------------------------
__global__ __launch_bounds__(256) void aconv(
    const float* __restrict__ A, unsigned short* __restrict__ H,
    unsigned short* __restrict__ L)
{
    int i = (blockIdx.x * 256 + threadIdx.x) * 8;
    float4 v0 = *(const float4*)&A[i];
    float4 v1 = *(const float4*)&A[i + 4];
    float vv[8] = {v0.x, v0.y, v0.z, v0.w, v1.x, v1.y, v1.z, v1.w};
    unsigned short hb[8], lb[8];
#pragma unroll
    for (int j = 0; j < 8; j++) {
        unsigned short h = f2bf_rn(vv[j]);
        hb[j] = h;
        lb[j] = f2bf_rn(vv[j] - bf2f(h));
    }
    *(float4*)&H[i] = *(float4*)hb;
    *(float4*)&L[i] = *(float4*)lb;
}

// ---------------------------------------------------------------------------
// bf16x3 MFMA GEMM — R24: same 64x64 tile, same LDS layout (40-stride),
// same register prefetch, same math as the proven R10 kernel — but 4 WAVES
// (256 threads) instead of 2. Each wave owns one 16-row strip (1 mt x 4 nt);
// staging is 1 slot/thread (was 2). Pure TLP change: waves/SIMD doubles on
// every launch (gemm3 had 2 of 4 SIMDs per CU completely idle at 128 thr).
// ---------------------------------------------------------------------------
__global__ __launch_bounds__(256) void gemm_bt(
    const unsigned short* __restrict__ Ah0, const unsigned short* __restrict__ Al0,
    const unsigned short* __restrict__ Bh0, const unsigned short* __restrict__ Bl0,
    float* __restrict__ C0, int K0, int N0, int T0,
    const unsigned short* __restrict__ Ah1, const unsigned short* __restrict__ Al1,
    const unsigned short* __restrict__ Bh1, const unsigned short* __restrict__ Bl1,
    float* __restrict__ C1, int K1, int N1, int T1,
    const unsigned short* __restrict__ Ah2, const unsigned short* __restrict__ Al2,
    const unsigned short* __restrict__ Bh2, const unsigned short* __restrict__ Bl2,
    float* __restrict__ C2, int K2, int N2, int T2)
{
    __shared__ unsigned short Ahs[64 * 40], Als[64 * 40];
    __shared__ unsigned short Bhs[64 * 40], Bls[64 * 40];

    int bx = blockIdx.x;
    const unsigned short *Ah, *Al, *Bh, *Bl; float* C; int K, N;
    if (bx < T0) {
        Ah = Ah0; Al = Al0; Bh = Bh0; Bl = Bl0; C = C0; K = K0; N = N0;
    } else if (bx < T0 + T1) {
        bx -= T0; Ah = Ah1; Al = Al1; Bh = Bh1; Bl = Bl1; C = C1; K = K1; N = N1;
    } else {
        bx -= T0 + T1; Ah = Ah2; Al = Al2; Bh = Bh2; Bl = Bl2; C = C2; K = K2; N = N2;
    }

    const int tid = threadIdx.x;
    const int w = tid >> 6, l = tid & 63;
    const int q = l >> 4, m16 = l & 15;
    const int bm = blockIdx.y * 64, bn = bx * 64;

    // staging: one 16B slot per thread (256 slots = 64 rows x 4 col-slots)
    const int r0 = tid >> 2, o0 = (tid & 3) * 8;
    const unsigned short* pAh0 = Ah + (size_t)(bm + r0) * K + o0;
    const unsigned short* pAl0 = Al + (size_t)(bm + r0) * K + o0;
    const unsigned short* pBh0 = Bh + (size_t)(bn + r0) * K + o0;
    const unsigned short* pBl0 = Bl + (size_t)(bn + r0) * K + o0;

    f32x4 acc[4];
#pragma unroll
    for (int j = 0; j < 4; j++)
        acc[j] = (f32x4){0.f, 0.f, 0.f, 0.f};

    float4 vAh0 = *(const float4*)pAh0;
    float4 vAl0 = *(const float4*)pAl0;
    float4 vBh0 = *(const float4*)pBh0;
    float4 vBl0 = *(const float4*)pBl0;

    for (int k0 = 0;; k0 += 32) {
        __syncthreads();
        *(float4*)&Ahs[r0 * 40 + o0] = vAh0;
        *(float4*)&Als[r0 * 40 + o0] = vAl0;
        *(float4*)&Bhs[r0 * 40 + o0] = vBh0;
        *(float4*)&Bls[r0 * 40 + o0] = vBl0;
        __syncthreads();

        const bool more = (k0 + 32) < K;
        if (more) {
            const int kn = k0 + 32;
            vAh0 = *(const float4*)(pAh0 + kn);
            vAl0 = *(const float4*)(pAl0 + kn);
            vBh0 = *(const float4*)(pBh0 + kn);
            vBl0 = *(const float4*)(pBl0 + kn);
        }

        short8 fah, fal, fbh[4], fbl[4];
        {
            const int row = w * 16 + m16;
            fah = *(const short8*)&Ahs[row * 40 + q * 8];
            fal = *(const short8*)&Als[row * 40 + q * 8];
        }
#pragma unroll
        for (int nt = 0; nt < 4; nt++) {
            const int row = nt * 16 + m16;
            fbh[nt] = *(const short8*)&Bhs[row * 40 + q * 8];
            fbl[nt] = *(const short8*)&Bls[row * 40 + q * 8];
        }
#pragma unroll
        for (int nt = 0; nt < 4; nt++) {
            acc[nt] = __builtin_amdgcn_mfma_f32_16x16x32_bf16(
                fah, fbh[nt], acc[nt], 0, 0, 0);
            acc[nt] = __builtin_amdgcn_mfma_f32_16x16x32_bf16(
                fah, fbl[nt], acc[nt], 0, 0, 0);
            acc[nt] = __builtin_amdgcn_mfma_f32_16x16x32_bf16(
                fal, fbh[nt], acc[nt], 0, 0, 0);
        }
        if (!more) break;
    }

#pragma unroll
    for (int nt = 0; nt < 4; nt++) {
        const int mrow = bm + w * 16 + q * 4;
        const int ncol = bn + nt * 16 + m16;
#pragma unroll
        for (int r = 0; r < 4; r++)
            C[(size_t)(mrow + r) * N + ncol] = acc[nt][r];
    }
}

// ---------------------------------------------------------------------------
// Fused RMSNorm (both norms in one launch; region-routed) -> bf16 hi/lo
// ---------------------------------------------------------------------------
__global__ __launch_bounds__(256) void rmsnorm_bf2(
    const float* __restrict__ in0, const float* __restrict__ w0,
    unsigned short* __restrict__ oh0, unsigned short* __restrict__ ol0,
    const float* __restrict__ in1, const float* __restrict__ w1,
    unsigned short* __restrict__ oh1, unsigned short* __restrict__ ol1)
{
    int bx = blockIdx.x;
    const float* in; const float* w; unsigned short *oh, *ol;
    int t, stride, ncols; float inv_n;
    if (bx < TT) {
        t = bx; in = in0; w = w0; oh = oh0; ol = ol0;
        stride = QLR; ncols = QLR; inv_n = 1.f / QLR;
    } else {
        t = bx - TT; in = in1; w = w1; oh = oh1; ol = ol1;
        stride = KVLR + DROPE; ncols = KVLR; inv_n = 1.f / KVLR;
    }
    const int tid = threadIdx.x;
    const float* row = in + (size_t)t * stride;
    float ss = 0.f;
    for (int c = tid; c < ncols; c += 256) { float v = row[c]; ss += v * v; }
#pragma unroll
    for (int m = 1; m < 64; m <<= 1) ss += __shfl_xor(ss, m);
    __shared__ float red[4];
    if ((tid & 63) == 0) red[tid >> 6] = ss;
    __syncthreads();
    float tot = red[0] + red[1] + red[2] + red[3];
    float scale = rsqrtf(tot * inv_n + 1e-5f);
    for (int c = tid; c < ncols; c += 256) {
        float v = row[c] * scale * w[c];
        unsigned short h = f2bf_rn(v);
        oh[(size_t)t * ncols + c] = h;
        ol[(size_t)t * ncols + c] = f2bf_rn(v - bf2f(h));
    }
}

// ---------------------------------------------------------------------------
// DPP reduction helpers
// ---------------------------------------------------------------------------
__device__ __forceinline__ float dpp_xor1(float x) {
    return __int_as_float(__builtin_amdgcn_update_dpp(
        0, __float_as_int(x), 0xB1, 0xF, 0xF, false));
}
__device__ __forceinline__ float dpp_xor2(float x) {
    return __int_as_float(__builtin_amdgcn_update_dpp(
        0, __float_as_int(x), 0x4E, 0xF, 0xF, false));
}
__device__ __forceinline__ float dpp_hm(float x) {   // row_half_mirror
    return __int_as_float(__builtin_amdgcn_update_dpp(
        0, __float_as_int(x), 0x141, 0xF, 0xF, false));
}
__device__ __forceinline__ float dpp_rm(float x) {   // row_mirror
    return __int_as_float(__builtin_amdgcn_update_dpp(
        0, __float_as_int(x), 0x140, 0xF, 0xF, false));
}
__device__ __forceinline__ float dpp_b15(float x) {  // row_bcast15
    return __int_as_float(__builtin_amdgcn_update_dpp(
        0, __float_as_int(x), 0x142, 0xF, 0xF, false));
}
__device__ __forceinline__ float red16(float x) {
    x += dpp_xor1(x);
    x += dpp_xor2(x);
    x += dpp_hm(x);
    x += dpp_rm(x);
    return x;
}
// 32-lane sum; result valid at lanes with (lane&31) in [16,32)
__device__ __forceinline__ float red32v(float x) {
    x += dpp_xor1(x);
    x += dpp_xor2(x);
    x += dpp_hm(x);
    x += dpp_rm(x);     // full 16-row sums in all lanes
    x += dpp_b15(x);    // rows 1,3 receive row 0,2 sums
    return x;
}

__device__ __forceinline__ void gl_lds16(const float* g, float* l) {
    __builtin_amdgcn_global_load_lds(
        (const __attribute__((address_space(1))) void*)g,
        (__attribute__((address_space(3))) void*)l, 16, 0, 0);
}

// ---------------------------------------------------------------------------
// Phase A — R23 fused version (verbatim from R8, best measured config).
// ---------------------------------------------------------------------------
__global__ __launch_bounds__(256) void chunk_prep(
    const float* __restrict__ qnraw, const float* __restrict__ agraw,
    const float* __restrict__ wg_b, const float* __restrict__ kvb,
    const float* __restrict__ kv_all, const float* __restrict__ x,
    const float* __restrict__ wb, float* __restrict__ pa)
{
    __shared__ float Ls[16][196];
    __shared__ float Ks[16][196];
    __shared__ float Qs[16][196];
    __shared__ float Ws[16][196];
    __shared__ float Xs[16][196];
    __shared__ float Ms[16][16];
    __shared__ float bs[16];
    __shared__ float kn[16], qn[16];

    const int tid = threadIdx.x;
    const int n = blockIdx.x >> 3, h = blockIdx.x & 7;
    const int t0 = n * 16;
    float* blob = pa + (size_t)blockIdx.x * PABLK;

    // ---- load raw Q / gate(->logsig) / K --------------------------------
#pragma unroll
    for (int s = 0; s < 3; s++) {
        int off = (tid * 3 + s) * 4;
        int r = off / 192, c = off - r * 192;
        *(float4*)&Qs[r][c] =
            *(const float4*)(qnraw + (size_t)(t0 + r) * HDK + h * DK + c);
        float4 g4 = *(const float4*)(agraw + (size_t)(t0 + r) * HDK + h * DK + c);
        float4 b4 = *(const float4*)(wg_b + h * DK + c);
        float4 la;
        {
            float z;
            z = g4.x + b4.x; la.x = fminf(z, 0.f) - log1pf(__expf(-fabsf(z)));
            z = g4.y + b4.y; la.y = fminf(z, 0.f) - log1pf(__expf(-fabsf(z)));
            z = g4.z + b4.z; la.z = fminf(z, 0.f) - log1pf(__expf(-fabsf(z)));
            z = g4.w + b4.w; la.w = fminf(z, 0.f) - log1pf(__expf(-fabsf(z)));
        }
        *(float4*)&Ls[r][c] = la;
        float4 kv;
        if (c < DNOPE)
            kv = *(const float4*)(kvb + (size_t)(t0 + r) * HKV + h * (DNOPE + DV) + c);
        else
            kv = *(const float4*)(kv_all + (size_t)(t0 + r) * (KVLR + DROPE) + KVLR + (c - DNOPE));
        *(float4*)&Ks[r][c] = kv;
    }
    // ---- beta: wave wv handles rows wv*4..wv*4+3 ------------------------
    {
        const int lane = tid & 63, wv = tid >> 6;
#pragma unroll
        for (int rr = 0; rr < 4; rr++) {
            const int r = wv * 4 + rr;
            const float* xr = x + (size_t)(t0 + r) * DIM;
            float ssum = 0.f;
            for (int e = lane; e < DIM; e += 64) ssum += xr[e] * wb[e * HH + h];
#pragma unroll
            for (int m = 1; m < 64; m <<= 1) ssum += __shfl_xor(ssum, m);
            if (lane == 0) bs[r] = 1.f / (1.f + expf(-ssum));
        }
    }
    __syncthreads();

    // ---- l2norm scales (16 threads per row, red16 within 16-lane group) -
    {
        const int i = tid >> 4, j = tid & 15;
        float sq = 0.f, sk = 0.f;
#pragma unroll
        for (int c4 = 0; c4 < 3; c4++) {
            float4 q4 = *(const float4*)&Qs[i][j * 12 + c4 * 4];
            float4 k4 = *(const float4*)&Ks[i][j * 12 + c4 * 4];
            sq += q4.x * q4.x + q4.y * q4.y + q4.z * q4.z + q4.w * q4.w;
            sk += k4.x * k4.x + k4.y * k4.y + k4.z * k4.z + k4.w * k4.w;
        }
        sq = red16(sq);
        sk = red16(sk);
        if (j == 0) {
            qn[i] = rsqrtf(sq + 1e-6f) * 0.07216878364870323f;  // * DK^-0.5
            kn[i] = rsqrtf(sk + 1e-6f);
        }
    }
    // ---- cumulative gate sums -------------------------------------------
    if (tid < 192) {
        float g = 0.f;
#pragma unroll
        for (int i = 0; i < 16; i++) { g += Ls[i][tid]; Ls[i][tid] = g; }
    }
    __syncthreads();

    // ---- scale by exp(G) and norms --------------------------------------
#pragma unroll
    for (int s = 0; s < 12; s++) {
        int idx = s * 256 + tid;
        int i = idx / 192, d = idx - i * 192;
        float G = Ls[i][d];
        float eg = __expf(G), en = __expf(-G);
        float kk = Ks[i][d] * kn[i];
        Ws[i][d] = bs[i] * kk * eg;
        Qs[i][d] = Qs[i][d] * qn[i] * eg;
        Ks[i][d] = kk * en;
    }
    __syncthreads();

#pragma unroll
    for (int s = 0; s < 3; s++) {
        int off = (tid * 3 + s) * 4;
        int r = off / 192, c = off - r * 192;
        *(float4*)(blob + OQ + off) = *(const float4*)&Qs[r][c];
    }
    if (tid < 192) {
        float lam = __expf(Ls[15][tid]);
        blob[OLAM + tid] = lam;
#pragma unroll
        for (int j4 = 0; j4 < 4; j4++) {
            float4 v;
            v.x = Ks[j4 * 4 + 0][tid] * lam; v.y = Ks[j4 * 4 + 1][tid] * lam;
            v.z = Ks[j4 * 4 + 2][tid] * lam; v.w = Ks[j4 * 4 + 3][tid] * lam;
            *(float4*)(blob + OC + tid * 20 + j4 * 4) = v;
        }
        blob[OC + tid * 20 + 16] = lam;
        blob[OC + tid * 20 + 17] = 0.f;
        blob[OC + tid * 20 + 18] = 0.f; blob[OC + tid * 20 + 19] = 0.f;
    }
    {
        const int i = tid >> 4, j = tid & 15;
        float m = 0.f, p = 0.f;
#pragma unroll
        for (int d4 = 0; d4 < 48; d4++) {
            float4 w  = *(const float4*)&Ws[i][d4 * 4];
            float4 ka = *(const float4*)&Ks[j][d4 * 4];
            float4 qa = *(const float4*)&Qs[i][d4 * 4];
            m += w.x * ka.x + w.y * ka.y + w.z * ka.z + w.w * ka.w;
            p += qa.x * ka.x + qa.y * ka.y + qa.z * ka.z + qa.w * ka.w;
        }
        Ms[i][j] = (j < i) ? m : 0.f;
        blob[OPL + tid] = (j <= i) ? p : 0.f;
    }
    __syncthreads();

    float y[16], uu[16];
    const bool doY = (tid < 192);
    const bool doU = (tid >= 128);
    const int dcol = tid, ccol = tid - 128;
    if (doY) {
#pragma unroll
        for (int i = 0; i < 16; i++) y[i] = Ws[i][dcol];
#pragma unroll
        for (int i = 1; i < 16; i++)
#pragma unroll
            for (int j = 0; j < i; j++)
                y[i] = fmaf(-Ms[i][j], y[j], y[i]);
    }
    if (doU) {
#pragma unroll
        for (int i = 0; i < 16; i++)
            uu[i] = bs[i] * kvb[(size_t)(t0 + i) * HKV + h * (DNOPE + DV) + DNOPE + ccol];
#pragma unroll
        for (int i = 1; i < 16; i++)
#pragma unroll
            for (int j = 0; j < i; j++)
                uu[i] = fmaf(-Ms[i][j], uu[j], uu[i]);
    }
    if (doY) {
#pragma unroll
        for (int i = 0; i < 16; i++) Xs[i][dcol] = y[i];
    }
    __syncthreads();
#pragma unroll
    for (int s = 0; s < 3; s++) {
        int off = (tid * 3 + s) * 4;
        int r = off / 192, c = off - r * 192;
        *(float4*)(blob + OY + off) = *(const float4*)&Xs[r][c];
    }
    // u' written transposed, straight from registers: [128 cc][16 ti]
    if (doU) {
#pragma unroll
        for (int i4 = 0; i4 < 4; i4++) {
            float4 t;
            t.x = uu[i4 * 4 + 0]; t.y = uu[i4 * 4 + 1];
            t.z = uu[i4 * 4 + 2]; t.w = uu[i4 * 4 + 3];
            *(float4*)(blob + OU + (size_t)ccol * 16 + i4 * 4) = t;
        }
    }
}

// ---------------------------------------------------------------------------
// Phase B — R18 dual-stream version verbatim (best measured config).
// ---------------------------------------------------------------------------
__global__ __launch_bounds__(1024) void kda_chunk(
    const float* __restrict__ pa, unsigned short* __restrict__ obh,
    unsigned short* __restrict__ obl)
{
    __shared__ float Cb[3][3840];
    __shared__ float Pb[3][256];
    __shared__ float ubs[3][64];    // u' slice [4 cc][16 ti]
    __shared__ float lbs[3][192];
    __shared__ float Ss[784];       // state [4 cc][196]
    __shared__ float us[80];        // u [4 cc][20]

    const int tid = threadIdx.x;
    const int w = tid >> 6, lane = tid & 63;
    const int h = blockIdx.x & 7, cg = blockIdx.x >> 3;   // XCD swizzle
    const int c0 = cg * 4;

    const int ti  = w;              // wave = time row (16 waves)
    const int ccs = lane >> 5;      // stream-local channel (0/1)
    const int dg  = lane & 31;      // 32 d-groups of 6
    const int dbase = dg * 6;

    auto stage = [&](int buf, int n) {
        const float* blob = pa + (size_t)(n * 8 + h) * PABLK;
        if (w < 15) {
            gl_lds16(blob + OC + w * 256 + lane * 4, &Cb[buf][w * 256]);
        } else {
            gl_lds16(blob + OPL + lane * 4, &Pb[buf][0]);
            if (lane < 16)
                gl_lds16(blob + OU + c0 * 16 + lane * 4, &ubs[buf][0]);
            if (lane < 48)
                gl_lds16(blob + OLAM + lane * 4, &lbs[buf][0]);
        }
    };

    auto ldYQ = [&](int n, float2 (&Y)[3], float2 (&Q)[3]) {
        const float* blob = pa + (size_t)(n * 8 + h) * PABLK;
        const float* py_ = blob + OY + ti * 192 + dbase;
        const float* pq_ = blob + OQ + ti * 192 + dbase;
#pragma unroll
        for (int s = 0; s < 3; s++) {
            Y[s] = *(const float2*)(py_ + s * 2);
            Q[s] = *(const float2*)(pq_ + s * 2);
        }
    };

    // P1(stream sbase in {0,2}): z/zq + u-write; returns zq (valid dg>=16)
    auto P1 = [&](int sbase, int bf, float2 (&Yr)[3], float2 (&Qr)[3]) -> float {
        const int r = sbase + ccs;
        const float* Sp = &Ss[r * 196 + dbase];
        float2 s0 = *(const float2*)Sp;
        float2 s1 = *(const float2*)(Sp + 2);
        float2 s2 = *(const float2*)(Sp + 4);
        float ubv = ubs[bf][r * 16 + ti];
        float py0 = Yr[0].x * s0.x, py1 = Yr[0].y * s0.y;
        float pq0 = Qr[0].x * s0.x, pq1 = Qr[0].y * s0.y;
        py0 = fmaf(Yr[1].x, s1.x, py0); py1 = fmaf(Yr[1].y, s1.y, py1);
        pq0 = fmaf(Qr[1].x, s1.x, pq0); pq1 = fmaf(Qr[1].y, s1.y, pq1);
        py0 = fmaf(Yr[2].x, s2.x, py0); py1 = fmaf(Yr[2].y, s2.y, py1);
        pq0 = fmaf(Qr[2].x, s2.x, pq0); pq1 = fmaf(Qr[2].y, s2.y, pq1);
        float zy = red32v(py0 + py1);
        float zq = red32v(pq0 + pq1);
        if (dg == 31) us[r * 20 + ti] = ubv - zy;
        return zq;
    };

    // P2(stream sbase): output (zq + P*u) and S-update.
    auto P2 = [&](int sbase, int bf, int n, float zq) {
        const int r = sbase + ccs;
        float pbvv = Pb[bf][ti * 16 + (dg & 15)];
        float usv  = us[r * 20 + (dg & 15)];
        float acc = (dg <= ti) ? pbvv * usv : 0.f;
        acc = red32v(acc);
        if (dg == 31) {
            float ov = zq + acc;
            if (isnan(ov)) ov = 0.f;
            else if (isinf(ov)) ov = ov > 0.f ? 1e4f : -1e4f;
            size_t oi = (size_t)(n * 16 + ti) * (HH * DV) + h * DV + c0 + r;
            unsigned short hb = f2bf_rn(ov);
            obh[oi] = hb;
            obl[oi] = f2bf_rn(ov - bf2f(hb));
        }
        if (tid < 384) {
            const int d = tid >> 1, c = (tid & 1) + sbase;
            const float4* up4 = (const float4*)&us[c * 20];
            float4 u0 = up4[0], u1 = up4[1], u2v = up4[2], u3 = up4[3];
            float svv = Ss[c * 196 + d];
            const float4* C4 = (const float4*)&Cb[bf][d * 20];
            float4 k0 = C4[0], k1 = C4[1], k2 = C4[2], k3 = C4[3];
            float a0 = lbs[bf][d] * svv, a1 = 0.f;
            a0 = fmaf(k0.x, u0.x,  a0); a1 = fmaf(k0.y, u0.y,  a1);
            a0 = fmaf(k0.z, u0.z,  a0); a1 = fmaf(k0.w, u0.w,  a1);
            a0 = fmaf(k1.x, u1.x,  a0); a1 = fmaf(k1.y, u1.y,  a1);
            a0 = fmaf(k1.z, u1.z,  a0); a1 = fmaf(k1.w, u1.w,  a1);
            a0 = fmaf(k2.x, u2v.x, a0); a1 = fmaf(k2.y, u2v.y, a1);
            a0 = fmaf(k2.z, u2v.z, a0); a1 = fmaf(k2.w, u2v.w, a1);
            a0 = fmaf(k3.x, u3.x,  a0); a1 = fmaf(k3.y, u3.y,  a1);
            a0 = fmaf(k3.z, u3.z,  a0); a1 = fmaf(k3.w, u3.w,  a1);
            Ss[c * 196 + d] = a0 + a1;
        }
    };

#define SEG_BAR asm volatile("s_waitcnt lgkmcnt(0)\n\ts_barrier" ::: "memory")

    float zqA, zqB;
    float2 Ya[3], Qa[3], Yb[3], Qb[3];

    // prologue
    for (int idx = tid; idx < 784; idx += 1024) Ss[idx] = 0.f;
    stage(0, 0);
    stage(1, 1);
    asm volatile("" ::: "memory");
    ldYQ(0, Ya, Qa);
    asm volatile("s_waitcnt vmcnt(0) lgkmcnt(0)\n\ts_barrier" ::: "memory");
    zqA = P1(0, 0, Ya, Qa);          // seg 0: A.P1(0)
    SEG_BAR;

    int bf = 0;
    for (int n = 0; n < 62; n += 2) {
        int bf1 = bf + 1; if (bf1 >= 3) bf1 -= 3;
        int bf2 = bf + 2; if (bf2 >= 3) bf2 -= 3;
        // ODD(n): stage(n+2), ldYQ(n+1); B.P1(n) ; A.P2(n)
        stage(bf2, n + 2);
        asm volatile("" ::: "memory");
        ldYQ(n + 1, Yb, Qb);
        zqB = P1(2, bf, Ya, Qa);
        P2(0, bf, n, zqA);
        SEG_BAR;
        // EVEN(n): A.P1(n+1) ; B.P2(n)
        zqA = P1(0, bf1, Yb, Qb);
        P2(2, bf, n, zqB);
        SEG_BAR;
        // ODD(n+1): stage(n+3), ldYQ(n+2); B.P1(n+1) ; A.P2(n+1)
        stage(bf, n + 3);
        asm volatile("" ::: "memory");
        ldYQ(n + 2, Ya, Qa);
        zqB = P1(2, bf1, Yb, Qb);
        P2(0, bf1, n + 1, zqA);
        SEG_BAR;
        // EVEN(n+1): A.P1(n+2) ; B.P2(n+1)
        zqA = P1(0, bf2, Ya, Qa);
        P2(2, bf1, n + 1, zqB);
        SEG_BAR;
        bf = bf2;
    }
    // bf = 62%3 = 2; Ya holds YQ(62); zqA = A.P1(62)
    {
        int bf1 = bf + 1; if (bf1 >= 3) bf1 -= 3;   // 63%3
        // ODD(62): ldYQ(63); B.P1(62) ; A.P2(62)
        ldYQ(63, Yb, Qb);
        zqB = P1(2, bf, Ya, Qa);
        P2(0, bf, 62, zqA);
        SEG_BAR;
        // EVEN(62): A.P1(63) ; B.P2(62)
        zqA = P1(0, bf1, Yb, Qb);
        P2(2, bf, 62, zqB);
        SEG_BAR;
        // ODD(63): B.P1(63) ; A.P2(63)
        zqB = P1(2, bf1, Yb, Qb);
        P2(0, bf1, 63, zqA);
        SEG_BAR;
        // seg 128: B.P2(63)
        P2(2, bf1, 63, zqB);
    }
#undef SEG_BAR
}

// ---------------------------------------------------------------------------
extern "C" void kernel_launch(void* const* d_in, const int* in_sizes, int n_in,
                              void* d_out, int out_size, void* d_ws, size_t ws_size,
                              hipStream_t stream)
{
    const float* x         = (const float*)d_in[0];
    // d_in[1] = cos, d_in[2] = sin : unused by the reference
    const float* wq_a      = (const float*)d_in[3];
    const float* q_norm_w  = (const float*)d_in[4];
    const float* wq_b      = (const float*)d_in[5];
    const float* wkv_a     = (const float*)d_in[6];
    const float* kv_norm_w = (const float*)d_in[7];
    const float* wkv_b     = (const float*)d_in[8];
    const float* wg_w      = (const float*)d_in[9];
    const float* wg_b      = (const float*)d_in[10];
    const float* wb        = (const float*)d_in[11];
    const float* wo        = (const float*)d_in[12];
    float* out = (float*)d_out;

    float* ws = (float*)d_ws;
    float* xq     = ws;                        // T x 768 (f32, gemm1 out)
    float* kv_all = xq     + TT * QLR;         // T x 576
    float* agraw  = kv_all + TT * (KVLR + DROPE); // T x 1536
    float* qnraw  = agraw  + TT * HDK;         // T x 1536
    float* kvb    = qnraw  + TT * HDK;         // T x 2048
    float* spare  = kvb    + TT * HKV;         // (was la_h/q_h/k_h/betab)
    float* pa     = spare  + 3 * TT * HDK + TT * HH;  // 512 x PABLK (25.6 MB)
    float* tail   = pa     + 512 * PABLK;

    unsigned short* wo_h  = (unsigned short*)tail;          // 1024*1024
    unsigned short* wo_l  = wo_h  + 1048576;
    unsigned short* xh    = wo_l  + 1048576;                // 1024*1024
    unsigned short* xl    = xh    + 1048576;
    unsigned short* xqh   = xl    + 1048576;                // 1024*768
    unsigned short* xql   = xqh   + 786432;
    unsigned short* kvnh  = xql   + 786432;                 // 1024*512
    unsigned short* kvnl  = kvnh  + 524288;

    unsigned short* wqa_h  = (unsigned short*)pa;           // 768n x 1024k
    unsigned short* wqa_l  = wqa_h  + 786432;
    unsigned short* wkva_h = wqa_l  + 786432;               // 576n x 1024k
    unsigned short* wkva_l = wkva_h + 589824;
    unsigned short* wgw_h  = wkva_l + 589824;               // 1536n x 1024k
    unsigned short* wgw_l  = wgw_h  + 1572864;
    unsigned short* wqb_h  = wgw_l  + 1572864;              // 1536n x 768k
    unsigned short* wqb_l  = wqb_h  + 1179648;
    unsigned short* wkvb_h = wqb_l  + 1179648;              // 2048n x 512k
    unsigned short* wkvb_l = wkvb_h + 1048576;

    unsigned short* obh = (unsigned short*)spare;           // 1024*1024
    unsigned short* obl = obh + 1048576;

    dim3 blk(256);

    wconv<<<dim3(192 + 144 + 384), blk, 0, stream>>>(
        wq_a, wqa_h, wqa_l, DIM, QLR, 192,
        wkv_a, wkva_h, wkva_l, DIM, KVLR + DROPE, 144,
        wg_w, wgw_h, wgw_l, DIM, HDK, 384);
    wconv<<<dim3(288 + 256 + 256), blk, 0, stream>>>(
        wq_b, wqb_h, wqb_l, QLR, HDK, 288,
        wkv_b, wkvb_h, wkvb_l, KVLR, HKV, 256,
        wo, wo_h, wo_l, DIM, DIM, 256);

    aconv<<<dim3(TT * DIM / (256 * 8)), blk, 0, stream>>>(x, xh, xl);

    gemm_bt<<<dim3(12 + 9 + 24, 16), dim3(256), 0, stream>>>(
        xh, xl, wqa_h, wqa_l, xq, DIM, QLR, 12,
        xh, xl, wkva_h, wkva_l, kv_all, DIM, KVLR + DROPE, 9,
        xh, xl, wgw_h, wgw_l, agraw, DIM, HDK, 24);

    rmsnorm_bf2<<<dim3(2 * TT), blk, 0, stream>>>(
        xq, q_norm_w, xqh, xql,
        kv_all, kv_norm_w, kvnh, kvnl);

    gemm_bt<<<dim3(24 + 32, 16), dim3(256), 0, stream>>>(
        xqh, xql, wqb_h, wqb_l, qnraw, QLR, HDK, 24,
        kvnh, kvnl, wkvb_h, wkvb_l, kvb, KVLR, HKV, 32,
        xh, xl, wqa_h, wqa_l, xq, DIM, QLR, 0);

    chunk_prep<<<512, blk, 0, stream>>>(
        qnraw, agraw, wg_b, kvb, kv_all, x, wb, pa);
    kda_chunk<<<256, dim3(1024), 0, stream>>>(pa, obh, obl);

    gemm_bt<<<dim3(16, 16), dim3(256), 0, stream>>>(
        obh, obl, wo_h, wo_l, out, DIM, DIM, 16,
        xh, xl, wqa_h, wqa_l, xq, DIM, QLR, 0,
        xh, xl, wqa_h, wqa_l, xq, DIM, QLR, 0);
}